// Round 6
// baseline (159.301 us; speedup 1.0000x reference)
//
#include <hip/hip_runtime.h>

typedef _Float16 half8 __attribute__((ext_vector_type(8)));
typedef _Float16 half4_t __attribute__((ext_vector_type(4)));
typedef float floatx4 __attribute__((ext_vector_type(4)));

// ---------------- prep: weight repack + fp16 x + fp16 c0 ----------------
// blocks [0,96): W1 (cols 1..128) and W2 into MFMA A-frag order (fp16)
// block 96: c0h = fp16 W1[:,0]
// blocks [97,..): xh = fp16 copy of x
__global__ __launch_bounds__(256) void prep_kernel(
    const float* __restrict__ x,
    const float* __restrict__ W1, const float* __restrict__ W2,
    _Float16* __restrict__ wsh, _Float16* __restrict__ c0h,
    _Float16* __restrict__ xh, int n_x8)
{
    int b = blockIdx.x;
    if (b < 96) {
        int tid = b * 256 + threadIdx.x;
        if (tid < 16384) {                    // W1: 8 mtiles x 4 kb x 512
            int c = tid >> 9, r = tid & 511;
            int L = r >> 3, jj = r & 7;
            int mt = c >> 2, kb = c & 3;
            int n = mt * 16 + (L & 15);
            int k = kb * 32 + (L >> 4) * 8 + jj;
            wsh[tid] = (_Float16)W1[n * 129 + 1 + k];
        } else {                              // W2: 4 mtiles x 4 kb x 512
            int t = tid - 16384;
            int c = t >> 9, r = t & 511;
            int L = r >> 3, jj = r & 7;
            int mt = c >> 2, kb = c & 3;
            int i = mt * 16 + (L & 15);
            int j = kb * 32 + (L >> 4) * 8 + jj;
            wsh[tid] = (_Float16)W2[i * 128 + j];
        }
    } else if (b == 96) {
        if (threadIdx.x < 128) c0h[threadIdx.x] = (_Float16)W1[threadIdx.x * 129];
    } else {
        int t2 = (b - 97) * 256 + threadIdx.x;
        if (t2 < n_x8) {
            const float4* p = (const float4*)(x + (size_t)t2 * 8);
            float4 v0 = p[0], v1 = p[1];
            half8 h = {(_Float16)v0.x, (_Float16)v0.y, (_Float16)v0.z, (_Float16)v0.w,
                       (_Float16)v1.x, (_Float16)v1.y, (_Float16)v1.z, (_Float16)v1.w};
            *(half8*)(xh + (size_t)t2 * 8) = h;
        }
    }
}

// ---------------- node projection: ys = W1s*x + b1, yt = W1t*x ----------------
// tab row (512 B) per node: [ys(128 fp16) | yt(128 fp16)]
__global__ __launch_bounds__(256) void node_proj_kernel(
    const _Float16* __restrict__ xh, const _Float16* __restrict__ wf,
    const float* __restrict__ b1, _Float16* __restrict__ tab, int N, int NTN)
{
    const int tid = threadIdx.x;
    const int lane = tid & 63, wave = tid >> 6;
    const int lrow = lane & 15, quad = lane >> 4;
    int nt = blockIdx.x * 4 + wave;
    if (nt >= NTN) return;
    int node = nt * 16 + lrow; if (node >= N) node = N - 1;

    half8 bfr0 = *(const half8*)(xh + (size_t)node * 64 + quad * 8);
    half8 bfr1 = *(const half8*)(xh + (size_t)node * 64 + 32 + quad * 8);

#pragma unroll
    for (int mt = 0; mt < 8; ++mt) {
        half8 a0 = *(const half8*)(wf + (mt * 4 + 0) * 512 + lane * 8);  // src cols, k 0..31
        half8 a1 = *(const half8*)(wf + (mt * 4 + 1) * 512 + lane * 8);  // src cols, k 32..63
        half8 a2 = *(const half8*)(wf + (mt * 4 + 2) * 512 + lane * 8);  // tgt cols
        half8 a3 = *(const half8*)(wf + (mt * 4 + 3) * 512 + lane * 8);
        floatx4 aS = {0.f, 0.f, 0.f, 0.f}, aT = {0.f, 0.f, 0.f, 0.f};
        aS = __builtin_amdgcn_mfma_f32_16x16x32_f16(a0, bfr0, aS, 0, 0, 0);
        aS = __builtin_amdgcn_mfma_f32_16x16x32_f16(a1, bfr1, aS, 0, 0, 0);
        aT = __builtin_amdgcn_mfma_f32_16x16x32_f16(a2, bfr0, aT, 0, 0, 0);
        aT = __builtin_amdgcn_mfma_f32_16x16x32_f16(a3, bfr1, aT, 0, 0, 0);
        floatx4 bb = *(const floatx4*)(b1 + mt * 16 + quad * 4);
        half4_t hS, hT;
#pragma unroll
        for (int r = 0; r < 4; ++r) {
            hS[r] = (_Float16)(aS[r] + bb[r]);   // fold b1 into ys
            hT[r] = (_Float16)aT[r];
        }
        *(half4_t*)(tab + (size_t)node * 256 + mt * 16 + quad * 4) = hS;
        *(half4_t*)(tab + (size_t)node * 256 + 128 + mt * 16 + quad * 4) = hT;
    }
}

// ---------------- edge kernel: gather tables -> h1 in B-frag regs -> L2+L3 ----------------
// No LDS, no barriers. Two-stage pipeline: tables(t+NW) + indices(t+2NW) issued
// before tile t's MFMAs. 16 edges per wave-tile.
__global__ __launch_bounds__(256, 2) void edge_kernel(
    const _Float16* __restrict__ tab,
    const int* __restrict__ ei,
    const float* __restrict__ ew,
    const _Float16* __restrict__ wf2,   // W2 frags (wsh + 16384)
    const _Float16* __restrict__ c0h,
    const float* __restrict__ b2, const float* __restrict__ W3,
    const float* __restrict__ b3,
    float* __restrict__ out, int E, int NT, int NW)
{
    const int tid = threadIdx.x;
    const int lane = tid & 63, wave = tid >> 6;
    const int lrow = lane & 15, quad = lane >> 4;

    // resident W2 fragments + params
    half8 w2f[4][4];
#pragma unroll
    for (int mt = 0; mt < 4; ++mt)
#pragma unroll
        for (int kb = 0; kb < 4; ++kb)
            w2f[mt][kb] = *(const half8*)(wf2 + (mt * 4 + kb) * 512 + lane * 8);
    half8 c0v[4];
#pragma unroll
    for (int kb = 0; kb < 4; ++kb)
        c0v[kb] = *(const half8*)(c0h + kb * 32 + quad * 8);
    floatx4 b2v[4], w3v[4];
#pragma unroll
    for (int mt = 0; mt < 4; ++mt) {
        b2v[mt] = *(const floatx4*)(b2 + mt * 16 + quad * 4);
        w3v[mt] = *(const floatx4*)(W3 + mt * 16 + quad * 4);
    }
    const float b3v = b3[0];

    int t = blockIdx.x * 4 + wave;
    if (t >= NT) return;

    // stage 0: indices(t) -> tables(t); indices(t+NW)
    int e0 = t * 16 + lrow; if (e0 >= E) e0 = E - 1;
    int s0 = ei[e0], d0 = ei[E + e0];
    float w0 = ew[e0];
    half8 ys0[4], yt0[4];
#pragma unroll
    for (int kb = 0; kb < 4; ++kb) {
        ys0[kb] = *(const half8*)(tab + (size_t)s0 * 256 + kb * 32 + quad * 8);
        yt0[kb] = *(const half8*)(tab + (size_t)d0 * 256 + 128 + kb * 32 + quad * 8);
    }
    int tn = t + NW;
    int tc1 = (tn < NT) ? tn : t;
    int e1 = tc1 * 16 + lrow; if (e1 >= E) e1 = E - 1;
    int s1 = ei[e1], d1 = ei[E + e1];
    float w1 = ew[e1];

    while (t < NT) {
        // issue tables(t+NW) (indices already resident)
        half8 ys1[4], yt1[4];
#pragma unroll
        for (int kb = 0; kb < 4; ++kb) {
            ys1[kb] = *(const half8*)(tab + (size_t)s1 * 256 + kb * 32 + quad * 8);
            yt1[kb] = *(const half8*)(tab + (size_t)d1 * 256 + 128 + kb * 32 + quad * 8);
        }
        // issue indices(t+2NW)
        int t2 = t + 2 * NW;
        int tc2 = (t2 < NT) ? t2 : t;
        int e2 = tc2 * 16 + lrow; if (e2 >= E) e2 = E - 1;
        int s2 = ei[e2], d2 = ei[E + e2];
        float w2s = ew[e2];

        // ---- compute tile t: h1 = relu(ys + yt + ew*c0), born in B-frag layout ----
        _Float16 ewh = (_Float16)w0;
        half8 hb[4];
#pragma unroll
        for (int kb = 0; kb < 4; ++kb) {
            half8 s = ys0[kb] + yt0[kb];
#pragma unroll
            for (int j = 0; j < 8; ++j) {
                _Float16 v = s[j] + ewh * c0v[kb][j];
                s[j] = v > (_Float16)0 ? v : (_Float16)0;
            }
            hb[kb] = s;
        }
        floatx4 acc[4];
#pragma unroll
        for (int mt = 0; mt < 4; ++mt) acc[mt] = b2v[mt];
#pragma unroll
        for (int kb = 0; kb < 4; ++kb)
#pragma unroll
            for (int mt = 0; mt < 4; ++mt)
                acc[mt] = __builtin_amdgcn_mfma_f32_16x16x32_f16(w2f[mt][kb], hb[kb], acc[mt], 0, 0, 0);

        float p = 0.f;
#pragma unroll
        for (int mt = 0; mt < 4; ++mt)
#pragma unroll
            for (int r = 0; r < 4; ++r)
                p += fmaxf(acc[mt][r], 0.f) * w3v[mt][r];
        p += __shfl_xor(p, 16, 64);
        p += __shfl_xor(p, 32, 64);
        int oe = t * 16 + lrow;
        if (quad == 0 && oe < E) out[oe] = p + b3v;

        // rotate pipeline
        t = tn;
        tn = t + NW;
        s0 = s1; d0 = d1; w0 = w1;
#pragma unroll
        for (int kb = 0; kb < 4; ++kb) { ys0[kb] = ys1[kb]; yt0[kb] = yt1[kb]; }
        s1 = s2; d1 = d2; w1 = w2s;
    }
}

extern "C" void kernel_launch(void* const* d_in, const int* in_sizes, int n_in,
                              void* d_out, int out_size, void* d_ws, size_t ws_size,
                              hipStream_t stream) {
    const float* x  = (const float*)d_in[0];
    const int*   ei = (const int*)d_in[1];   // int32 (verified round 1)
    const float* ew = (const float*)d_in[2];
    const float* W1 = (const float*)d_in[3];
    const float* b1 = (const float*)d_in[4];
    const float* W2 = (const float*)d_in[5];
    const float* b2 = (const float*)d_in[6];
    const float* W3 = (const float*)d_in[7];
    const float* b3 = (const float*)d_in[8];
    float* out = (float*)d_out;
    const int E  = in_sizes[2];              // n_edges
    const int n_x = in_sizes[0];
    const int N  = n_x / 64;                 // n_nodes
    const int n_x8 = n_x / 8;

    // workspace layout
    _Float16* wsh = (_Float16*)d_ws;                        // 48 KiB weight frags
    _Float16* c0h = (_Float16*)((char*)d_ws + 49152);       // 256 B fp16 c0
    _Float16* xh  = (_Float16*)((char*)d_ws + 51200);       // 6.4 MB fp16 x
    _Float16* tab = (_Float16*)((char*)d_ws + 6604800);     // 25.6 MB node tables

    int xblk = (n_x8 + 255) / 256;
    prep_kernel<<<97 + xblk, 256, 0, stream>>>(x, W1, W2, wsh, c0h, xh, n_x8);

    const int NTN = (N + 15) / 16;
    node_proj_kernel<<<(NTN + 3) / 4, 256, 0, stream>>>(xh, wsh, b1, tab, N, NTN);

    const int NT = (E + 15) / 16;
    int grid = 2048;
    if (grid > (NT + 3) / 4) grid = (NT + 3) / 4;
    const int NW = grid * 4;
    edge_kernel<<<grid, 256, 0, stream>>>(tab, ei, ew, wsh + 16384, c0h,
                                          b2, W3, b3, out, E, NT, NW);
}